// Round 12
// baseline (166.208 us; speedup 1.0000x reference)
//
#include <hip/hip_runtime.h>
#include <math.h>

static constexpr float EPSF = 1e-5f;

typedef short bf16x8 __attribute__((ext_vector_type(8)));
typedef float f32x4 __attribute__((ext_vector_type(4)));
typedef ushort u16x8 __attribute__((ext_vector_type(8)));

__device__ inline ushort bf16rn(float f) {
  unsigned u = __float_as_uint(f);
  unsigned r = (u + 0x7FFFu + ((u >> 16) & 1u)) >> 16;
  return (ushort)r;
}
__device__ inline float bf2f(ushort u) { return __uint_as_float(((unsigned)u) << 16); }
__device__ inline void split2(float f, ushort& hi, ushort& lo) {
  ushort h = bf16rn(f);
  float hf = bf2f(h);
  hi = h;
  lo = bf16rn(f - hf);
}
// tanh via hw exp+rcp: exact at saturation, ~1e-7 abs err
__device__ inline float fast_tanh(float x) {
  float e = __expf(2.f * x);
  return 1.f - 2.f * __builtin_amdgcn_rcpf(e + 1.f);
}

__device__ inline void gload16(const ushort* g, ushort* l) {
  __builtin_amdgcn_global_load_lds((const __attribute__((address_space(1))) void*)g,
                                   (__attribute__((address_space(3))) void*)l, 16, 0, 0);
}

// Tiled layout (ushort index): addr(row,k) = (row>>7)*65536 + (k>>5)*4096
//   + ((k>>3)&3)*1024 + (row&127)*8 + (k&7)
__device__ inline size_t tiled_addr(int row, int k) {
  return (size_t)(row >> 7) * 65536 + (size_t)(k >> 5) * 4096 +
         (size_t)((k >> 3) & 3) * 1024 + (size_t)(row & 127) * 8 + (k & 7);
}

// ---------------- K1: fused convx (0..4095) + pack_w (4096..4351) + pack_pw (4352..4367) ----------------
__global__ __launch_bounds__(256) void conv_pack(
    const float* __restrict__ x,
    const float* __restrict__ o_xj, const float* __restrict__ o_xi,
    const float* __restrict__ rel_o_xj, const float* __restrict__ rel_o_xi,
    const float* __restrict__ p_xj, const float* __restrict__ p_xi,
    ushort* __restrict__ xhi, ushort* __restrict__ xthi,
    ushort* __restrict__ wjhi, ushort* __restrict__ wihi,
    ushort* __restrict__ Wthi, ushort* __restrict__ Wtlo,
    float* __restrict__ colWs,
    float* __restrict__ bpart,
    int* __restrict__ cnt) {
  const int bx = blockIdx.x;
  const int tid = threadIdx.x;
  if (bx >= 4352) {
    // ---- pack_pw: p_xj/p_xi -> Wt[path][d][q][512] bf16 hi/lo + colWs ----
    const int pd = bx - 4352;            // 0..15
    if (pd == 0 && tid < 64) cnt[tid] = 0;   // zero finisher counters each call
    const int path = pd >> 3, d = pd & 7;
    const float* src = (path ? p_xi : p_xj) + (size_t)d * 16384;
    ushort* whi = Wthi + (size_t)pd * 16384;
    ushort* wlo = Wtlo + (size_t)pd * 16384;
    __shared__ float buf[64][33];
    float cw = 0.f;
    const int q = tid >> 3, je8 = (tid & 7) * 8;
    for (int j0 = 0; j0 < 512; j0 += 64) {
      for (int l = tid; l < 2048; l += 256) buf[l >> 5][l & 31] = src[(size_t)j0 * 32 + l];
      __syncthreads();
      u16x8 h8, l8;
      #pragma unroll
      for (int e = 0; e < 8; ++e) {
        float fv = buf[je8 + e][q];
        cw += fv;
        ushort h, l; split2(fv, h, l);
        h8[e] = h; l8[e] = l;
      }
      *reinterpret_cast<u16x8*>(&whi[(size_t)q * 512 + j0 + je8]) = h8;
      *reinterpret_cast<u16x8*>(&wlo[(size_t)q * 512 + j0 + je8]) = l8;
      __syncthreads();
    }
    cw += __shfl_xor(cw, 1); cw += __shfl_xor(cw, 2); cw += __shfl_xor(cw, 4);
    if ((tid & 7) == 0) colWs[(size_t)pd * 32 + q] = cw;
    return;
  }
  if (bx >= 4096) {
    // ---- pack_w (o-weights, tiled bf16) ----
    int u = (bx - 4096) * 256 + tid;   // 0..65535
    int path = u >> 15;
    int v = u & 32767;
    int c = v >> 6;
    int k0 = (v & 63) * 8;
    int d = c >> 6, s = (c >> 5) & 1, p = c & 31;
    const float* src = path ? (s ? rel_o_xi : o_xi) : (s ? rel_o_xj : o_xj);
    u16x8 h8;
    #pragma unroll
    for (int e = 0; e < 8; ++e) h8[e] = bf16rn(src[((size_t)d * 512 + k0 + e) * 32 + p]);
    size_t a = tiled_addr(c, k0);
    ushort* whi = path ? wihi : wjhi;
    *reinterpret_cast<u16x8*>(&whi[a]) = h8;
    return;
  }
  // ---- convx part ----
  __shared__ float tile[64][65];
  __shared__ float wsum[4], wsq[4];
  const int ti = bx & 7, tj = (bx >> 3) & 7, b = bx >> 6;
  const int i0 = ti * 64, j0 = tj * 64;
  const float* xb = x + (size_t)b * 262144;
  const size_t obase = (size_t)b * 262144;
  const int tr = tid >> 4;
  const int tc = (tid & 15) * 4;
  float s = 0.f, s2 = 0.f;
  #pragma unroll
  for (int r = 0; r < 4; ++r) {
    const int row = r * 16 + tr;
    float4 v = *reinterpret_cast<const float4*>(&xb[(size_t)(i0 + row) * 512 + j0 + tc]);
    tile[row][tc + 0] = v.x; tile[row][tc + 1] = v.y;
    tile[row][tc + 2] = v.z; tile[row][tc + 3] = v.w;
    s += v.x + v.y + v.z + v.w;
    s2 += v.x * v.x + v.y * v.y + v.z * v.z + v.w * v.w;
  }
  // wave-level stat reduce (no barrier tree)
  #pragma unroll
  for (int m = 1; m < 64; m <<= 1) { s += __shfl_xor(s, m); s2 += __shfl_xor(s2, m); }
  if ((tid & 63) == 0) { wsum[tid >> 6] = s; wsq[tid >> 6] = s2; }
  __syncthreads();
  if (tid == 0) {
    float* pb = bpart + ((size_t)b * 64 + tj * 8 + ti) * 2;
    pb[0] = wsum[0] + wsum[1] + wsum[2] + wsum[3];
    pb[1] = wsq[0] + wsq[1] + wsq[2] + wsq[3];
  }
  const int kg = tid >> 5;   // 0..7
  const int rp = tid & 31;
  #pragma unroll
  for (int rr = 0; rr < 2; ++rr) {
    const int li = rp + rr * 32;
    u16x8 h8;
    #pragma unroll
    for (int e = 0; e < 8; ++e) h8[e] = bf16rn(tile[li][kg * 8 + e]);
    *reinterpret_cast<u16x8*>(&xhi[obase + tiled_addr(i0 + li, j0 + kg * 8)]) = h8;
  }
  #pragma unroll
  for (int rr = 0; rr < 2; ++rr) {
    const int lj = rp + rr * 32;
    u16x8 h8;
    #pragma unroll
    for (int e = 0; e < 8; ++e) h8[e] = bf16rn(tile[kg * 8 + e][lj]);
    *reinterpret_cast<u16x8*>(&xthi[obase + tiled_addr(j0 + lj, i0 + kg * 8)]) = h8;
  }
}

// ---------------- K2: pure-bf16 MFMA GEMM (R8-proven structure, BK=32) ----------------
// T output written TRANSPOSED: Tt[b][d][p 32][i 512] (bf16).
__global__ __launch_bounds__(256) void mfma_gemm(
    const ushort* __restrict__ xhi, const ushort* __restrict__ xthi,
    const ushort* __restrict__ wjhi, const ushort* __restrict__ wihi,
    ushort* __restrict__ Ttj, ushort* __restrict__ Tti,
    float* __restrict__ pJ, float* __restrict__ pI) {
  const int id = blockIdx.x;
  const int wid = (id & 7) * 256 + (id >> 3);   // XCD-aware swizzle (2048 = 8*256)
  const int ct = wid & 3, tm = (wid >> 2) & 3, bz = wid >> 4;
  const int b = bz >> 1, path = bz & 1;
  const ushort* Ahi = (path ? xthi : xhi) + (size_t)b * 262144 + (size_t)tm * 65536;
  const ushort* Bhi = (path ? wihi : wjhi) + (size_t)ct * 65536;
  ushort* Tb = (path ? Tti : Ttj) + (size_t)b * 131072;
  float* partial = path ? pI : pJ;

  __shared__ alignas(16) ushort As_hi[4096], Bs_hi[4096];
  __shared__ float rsum[4], rsq[4], rcol[4][32];

  const int tid = threadIdx.x;
  const int lane = tid & 63, w = tid >> 6;
  const int wr = w >> 1, wc = w & 1;
  const int m0 = tm * 128;

  const int L8 = (w * 64 + lane) * 8;
  const int ldsb0 = (w * 64) * 8;
  const int ldsb1 = 2048 + (w * 64) * 8;

  f32x4 acc[4][4] = {};
  const int fr = lane & 15;
  const int kc = lane >> 4;

  for (int ks = 0; ks < 16; ++ks) {
    const ushort* Ah = Ahi + ks * 4096;
    const ushort* Bh = Bhi + ks * 4096;
    gload16(Ah + L8,        &As_hi[ldsb0]);
    gload16(Ah + 2048 + L8, &As_hi[ldsb1]);
    gload16(Bh + L8,        &Bs_hi[ldsb0]);
    gload16(Bh + 2048 + L8, &Bs_hi[ldsb1]);
    __syncthreads();
    bf16x8 ah[4], bh[4];
    #pragma unroll
    for (int mi = 0; mi < 4; ++mi) {
      const int ra = (kc * 128 + wr * 64 + mi * 16 + fr) * 8;
      ah[mi] = *reinterpret_cast<const bf16x8*>(&As_hi[ra]);
    }
    #pragma unroll
    for (int ni = 0; ni < 4; ++ni) {
      const int rb = (kc * 128 + wc * 64 + ni * 16 + fr) * 8;
      bh[ni] = *reinterpret_cast<const bf16x8*>(&Bs_hi[rb]);
    }
    #pragma unroll
    for (int mi = 0; mi < 4; ++mi)
      #pragma unroll
      for (int ni = 0; ni < 4; ++ni)
        acc[mi][ni] = __builtin_amdgcn_mfma_f32_16x16x32_bf16(ah[mi], bh[ni], acc[mi][ni], 0, 0, 0);
    __syncthreads();
  }

  float lsum = 0.f, lsq = 0.f, cs0 = 0.f, cs1 = 0.f;
  const int d = ct * 2 + wc;
  #pragma unroll
  for (int mi = 0; mi < 4; ++mi) {
    const int rbase = m0 + wr * 64 + mi * 16 + ((lane >> 4) << 2);
    #pragma unroll
    for (int ni = 0; ni < 4; ++ni) {
      if (ni < 2) {
        const int p = ni * 16 + fr;
        float t0 = fast_tanh(acc[mi][ni][0]);
        float t1 = fast_tanh(acc[mi][ni][1]);
        float t2 = fast_tanh(acc[mi][ni][2]);
        float t3 = fast_tanh(acc[mi][ni][3]);
        lsum += t0 + t1 + t2 + t3;
        lsq += t0 * t0 + t1 * t1 + t2 * t2 + t3 * t3;
        ushort4 pk;
        pk.x = bf16rn(t0); pk.y = bf16rn(t1); pk.z = bf16rn(t2); pk.w = bf16rn(t3);
        *reinterpret_cast<ushort4*>(&Tb[((size_t)d * 32 + p) * 512 + rbase]) = pk;
      } else {
        #pragma unroll
        for (int r = 0; r < 4; ++r) {
          float e = __expf(acc[mi][ni][r]);
          if (ni == 2) cs0 += e; else cs1 += e;
        }
      }
    }
  }
  #pragma unroll
  for (int m = 1; m < 64; m <<= 1) { lsum += __shfl_xor(lsum, m); lsq += __shfl_xor(lsq, m); }
  cs0 += __shfl_xor(cs0, 16); cs0 += __shfl_xor(cs0, 32);
  cs1 += __shfl_xor(cs1, 16); cs1 += __shfl_xor(cs1, 32);
  if (lane == 0) { rsum[w] = lsum; rsq[w] = lsq; }
  if (lane < 16) { rcol[w][lane] = cs0; rcol[w][16 + lane] = cs1; }
  __syncthreads();
  if (tid < 64) {
    const int wc2 = tid >> 5, p = tid & 31;
    float* pb = partial + (((size_t)b * 4 + tm) * 8 + ct * 2 + wc2) * 34;
    pb[2 + p] = rcol[wc2][p] + rcol[wc2 + 2][p];
    if (p == 0) {
      pb[0] = rsum[wc2] + rsum[wc2 + 2];
      pb[1] = rsq[wc2] + rsq[wc2 + 2];
    }
  }
}

// ---------------- K3: fused stage3 (folds gemm partials; last block per b sums d -> out) ----------------
// Block per (b,d). Waves: w = path*2 + mt.
__global__ __launch_bounds__(256) void stage3_fused(
    const ushort* __restrict__ Ttj, const ushort* __restrict__ Tti,
    const ushort* __restrict__ Wthi, const ushort* __restrict__ Wtlo,
    const float* __restrict__ colWs,
    const float* __restrict__ rel_pj, const float* __restrict__ rel_pi,
    const float* __restrict__ pJ, const float* __restrict__ pI,
    const float* __restrict__ bpart,
    const float* __restrict__ gamma_p, const float* __restrict__ beta_p,
    float* __restrict__ xball, int* __restrict__ cnt, float* __restrict__ out) {
  const int bd = blockIdx.x;
  const int b = bd >> 3, d = bd & 7;
  const int tid = threadIdx.x;
  const int lane = tid & 63, w = tid >> 6;
  const int path = w >> 1, mt = w & 1;
  const int fr = lane & 15, kg = lane >> 4;

  __shared__ float Vl[2][32][33];
  __shared__ float Rl[2][32][32];
  __shared__ float cred[2][32][33];
  __shared__ float colw_s[64];
  __shared__ float stS[2][34];     // folded raw sums: [path]{sum,sumsq,col[32]}
  __shared__ float ms[2][2];       // [path]{mean, rstd}
  __shared__ float orelT[2];
  __shared__ float pred[4][2];
  __shared__ float csum[2][32];
  __shared__ float stot[2];
  __shared__ float fsc[2][32];
  __shared__ float red[256], red2[256];
  __shared__ float sred[2], sbst[2];
  __shared__ int lastFlag;

  // stage R matrices, colW, folded stats, batch stats
  for (int l = tid; l < 2048; l += 256) {
    const int pp = l >> 10, idx = l & 1023;
    const float* Rsrc = pp ? rel_pi : rel_pj;
    Rl[pp][idx >> 5][idx & 31] = Rsrc[(size_t)d * 1024 + idx];
  }
  if (tid < 64) colw_s[tid] = colWs[(((size_t)(tid >> 5) * 8 + d)) * 32 + (tid & 31)];
  if (tid >= 64 && tid < 132) {
    const int u = tid - 64;
    const int pp = u >= 34, t = pp ? u - 34 : u;
    const float* P = pp ? pI : pJ;
    float v = 0.f;
    #pragma unroll
    for (int tm2 = 0; tm2 < 4; ++tm2) v += P[(((size_t)b * 4 + tm2) * 8 + d) * 34 + t];
    stS[pp][t] = v;
  }
  if (tid >= 192) {
    const int t = tid - 192;
    float s = bpart[(size_t)b * 128 + t * 2];
    float s2 = bpart[(size_t)b * 128 + t * 2 + 1];
    #pragma unroll
    for (int m = 1; m < 64; m <<= 1) { s += __shfl_xor(s, m); s2 += __shfl_xor(s2, m); }
    if (t == 0) {
      const float N = 262144.f;
      float mean = s / N;
      float var = (s2 - s * s / N) / (N - 1.f);
      sbst[0] = mean * 256.f;
      sbst[1] = sqrtf(fmaxf(var, 0.f)) * 256.f;
    }
  }
  __syncthreads();
  if (tid < 2) {
    const float* S = stS[tid];
    const float N = 16384.f;
    float mean = S[0] / N;
    float var = (S[1] - S[0] * S[0] / N) / (N - 1.f);
    ms[tid][0] = mean;
    ms[tid][1] = 1.f / (sqrtf(fmaxf(var, 0.f)) + EPSF);
    float tot = 0.f;
    for (int k = 0; k < 32; ++k) tot += S[2 + k];
    orelT[tid] = tot;
  }

  // ---- MFMA projection: 16 rows (this wave) x 32 cols, K=512 ----
  f32x4 acc0 = {}, acc1 = {};
  const ushort* Whi_p = Wthi + ((size_t)path * 8 + d) * 16384;
  const ushort* Wlo_p = Wtlo + ((size_t)path * 8 + d) * 16384;
  const ushort* Tp = (path ? Tti : Ttj) + ((size_t)b * 8 + d) * 16384;

  if (path == 0) {
    const ushort* Arow = Tp + (size_t)(mt * 16 + fr) * 512;
    const ushort* B0h = Whi_p + (size_t)fr * 512;
    const ushort* B0l = Wlo_p + (size_t)fr * 512;
    const ushort* B1h = Whi_p + (size_t)(16 + fr) * 512;
    const ushort* B1l = Wlo_p + (size_t)(16 + fr) * 512;
    for (int k0 = 0; k0 < 512; k0 += 32) {
      const int ko = k0 + kg * 8;
      bf16x8 a   = *reinterpret_cast<const bf16x8*>(Arow + ko);
      bf16x8 b0h = *reinterpret_cast<const bf16x8*>(B0h + ko);
      bf16x8 b0l = *reinterpret_cast<const bf16x8*>(B0l + ko);
      bf16x8 b1h = *reinterpret_cast<const bf16x8*>(B1h + ko);
      bf16x8 b1l = *reinterpret_cast<const bf16x8*>(B1l + ko);
      acc0 = __builtin_amdgcn_mfma_f32_16x16x32_bf16(a, b0h, acc0, 0, 0, 0);
      acc0 = __builtin_amdgcn_mfma_f32_16x16x32_bf16(a, b0l, acc0, 0, 0, 0);
      acc1 = __builtin_amdgcn_mfma_f32_16x16x32_bf16(a, b1h, acc1, 0, 0, 0);
      acc1 = __builtin_amdgcn_mfma_f32_16x16x32_bf16(a, b1l, acc1, 0, 0, 0);
    }
  } else {
    const ushort* Ahr = Whi_p + (size_t)(mt * 16 + fr) * 512;
    const ushort* Alr = Wlo_p + (size_t)(mt * 16 + fr) * 512;
    const ushort* B0 = Tp + (size_t)fr * 512;
    const ushort* B1 = Tp + (size_t)(16 + fr) * 512;
    for (int k0 = 0; k0 < 512; k0 += 32) {
      const int ko = k0 + kg * 8;
      bf16x8 ah = *reinterpret_cast<const bf16x8*>(Ahr + ko);
      bf16x8 al = *reinterpret_cast<const bf16x8*>(Alr + ko);
      bf16x8 b0 = *reinterpret_cast<const bf16x8*>(B0 + ko);
      bf16x8 b1 = *reinterpret_cast<const bf16x8*>(B1 + ko);
      acc0 = __builtin_amdgcn_mfma_f32_16x16x32_bf16(ah, b0, acc0, 0, 0, 0);
      acc0 = __builtin_amdgcn_mfma_f32_16x16x32_bf16(al, b0, acc0, 0, 0, 0);
      acc1 = __builtin_amdgcn_mfma_f32_16x16x32_bf16(ah, b1, acc1, 0, 0, 0);
      acc1 = __builtin_amdgcn_mfma_f32_16x16x32_bf16(al, b1, acc1, 0, 0, 0);
    }
  }
  __syncthreads();   // ms/orelT ready (also covers stS)

  // ---- corrected standardize + tanh ----
  const float mean = ms[path][0], rstd = ms[path][1];
  float tv0[4], tv1[4];
  float ls = 0.f, lq = 0.f;
  #pragma unroll
  for (int r = 0; r < 4; ++r) {
    const int rowm = mt * 16 + kg * 4 + r;
    {
      const float cw = (path == 0) ? colw_s[fr] : colw_s[32 + rowm];
      float t = fast_tanh((acc0[r] - mean * cw) * rstd);
      tv0[r] = t; ls += t; lq += t * t;
    }
    {
      const float cw = (path == 0) ? colw_s[16 + fr] : colw_s[32 + rowm];
      float t = fast_tanh((acc1[r] - mean * cw) * rstd);
      tv1[r] = t; ls += t; lq += t * t;
    }
  }
  #pragma unroll
  for (int m = 1; m < 64; m <<= 1) { ls += __shfl_xor(ls, m); lq += __shfl_xor(lq, m); }
  if (lane == 0) { pred[w][0] = ls; pred[w][1] = lq; }
  __syncthreads();
  {
    const float S = pred[path * 2][0] + pred[path * 2 + 1][0];
    const float SS = pred[path * 2][1] + pred[path * 2 + 1][1];
    const float m2 = S / 1024.f;
    const float var = (SS - S * S / 1024.f) / 1023.f;
    const float r2 = 1.f / (sqrtf(fmaxf(var, 0.f)) + EPSF);
    #pragma unroll
    for (int r = 0; r < 4; ++r) {
      const int rowm = mt * 16 + kg * 4 + r;
      Vl[path][rowm][fr] = (tv0[r] - m2) * r2;
      Vl[path][rowm][16 + fr] = (tv1[r] - m2) * r2;
    }
  }
  __syncthreads();

  // ---- rel matmul + exp (128 threads per path) ----
  {
    const int t2 = tid & 127;
    const int prow = t2 >> 2, c8 = (t2 & 3) * 8;
    float racc[8] = {};
    #pragma unroll
    for (int c = 0; c < 32; ++c) {
      const float v = Vl[path][prow][c];
      #pragma unroll
      for (int e = 0; e < 8; ++e) racc[e] = fmaf(v, Rl[path][c][c8 + e], racc[e]);
    }
    #pragma unroll
    for (int e = 0; e < 8; ++e) cred[path][prow][c8 + e] = __expf(racc[e]);
  }
  __syncthreads();
  if (tid < 64) {
    const int pp = tid >> 5, q = tid & 31;
    float s = 0.f;
    #pragma unroll 8
    for (int p = 0; p < 32; ++p) s += cred[pp][p][q];
    csum[pp][q] = s;
  }
  __syncthreads();
  if (tid < 2) {
    float tot = 0.f;
    for (int k = 0; k < 32; ++k) tot += csum[tid][k];
    stot[tid] = tot;
  }
  __syncthreads();
  if (tid < 64) {
    const int pp = tid >> 5, q = tid & 31;
    fsc[pp][q] = sqrtf((stS[pp][2 + q] / orelT[pp]) * stot[pp] / csum[pp][q]);
  }
  __syncthreads();

  // ---- combine ----
  const int row = tid >> 3, c4 = (tid & 7) * 4;
  float xv[4]; float ls2 = 0.f, lq2 = 0.f;
  #pragma unroll
  for (int e = 0; e < 4; ++e) {
    const int q = c4 + e;
    float v = fast_tanh(Vl[0][row][q] * fsc[0][row] * Vl[1][q][row] * fsc[1][q]);
    xv[e] = v; ls2 += v; lq2 += v * v;
  }
  red[tid] = ls2; red2[tid] = lq2;
  __syncthreads();
  for (int off = 128; off > 0; off >>= 1) {
    if (tid < off) { red[tid] += red[tid + off]; red2[tid] += red2[tid + off]; }
    __syncthreads();
  }
  if (tid == 0) {
    float s = red[0], ss = red2[0];
    float m = s / 1024.f;
    float var = (ss - s * s / 1024.f) / 1023.f;
    sred[0] = m; sred[1] = 1.f / (sqrtf(fmaxf(var, 0.f)) + EPSF);
  }
  __syncthreads();
  const float m3 = sred[0], r3 = sred[1];
  const float xm = sbst[0], xs = sbst[1];
  const float g = gamma_p[d], be = beta_p[d];
  #pragma unroll
  for (int e = 0; e < 4; ++e) {
    float v = (xv[e] - m3) * r3 * xs + xm;
    xball[(size_t)bd * 1024 + row * 32 + c4 + e] = v * g + be;
  }

  // ---- last block per b: fold d -> out (deterministic fixed-order sum) ----
  __threadfence();
  __syncthreads();
  if (tid == 0) {
    int old = atomicAdd(&cnt[b], 1);
    lastFlag = (old == 7) ? 1 : 0;
  }
  __syncthreads();
  if (lastFlag) {
    __threadfence();   // acquire: other blocks' xball writes
    for (int e = tid; e < 1024; e += 256) {
      float s = 0.f;
      #pragma unroll
      for (int dd = 0; dd < 8; ++dd) s += xball[((size_t)(b * 8 + dd)) * 1024 + e];
      out[(size_t)b * 1024 + e] = s * 0.125f;
    }
    if (tid == 0) cnt[b] = 0;   // self-reset for graph replay
  }
}

extern "C" void kernel_launch(void* const* d_in, const int* in_sizes, int n_in,
                              void* d_out, int out_size, void* d_ws, size_t ws_size,
                              hipStream_t stream) {
  const float* x        = (const float*)d_in[0];
  const float* o_xj     = (const float*)d_in[1];
  const float* o_xi     = (const float*)d_in[2];
  const float* p_xj     = (const float*)d_in[3];
  const float* p_xi     = (const float*)d_in[4];
  const float* rel_o_xj = (const float*)d_in[5];
  const float* rel_o_xi = (const float*)d_in[6];
  const float* rel_p_xj = (const float*)d_in[7];
  const float* rel_p_xi = (const float*)d_in[8];
  const float* gamma_p  = (const float*)d_in[9];
  const float* beta_p   = (const float*)d_in[10];
  float* out = (float*)d_out;

  char* base = (char*)d_ws;
  ushort* xhi  = (ushort*)base; base += (size_t)33554432;
  ushort* xthi = (ushort*)base; base += (size_t)33554432;
  ushort* wjhi = (ushort*)base; base += 524288;
  ushort* wihi = (ushort*)base; base += 524288;
  ushort* Ttj  = (ushort*)base; base += (size_t)16777216;
  ushort* Tti  = (ushort*)base; base += (size_t)16777216;
  ushort* Wthi = (ushort*)base; base += 524288;
  ushort* Wtlo = (ushort*)base; base += 524288;
  float* colWs = (float*)base;  base += 2048;
  float* pJ    = (float*)base;  base += 278528;
  float* pI    = (float*)base;  base += 278528;
  float* bpart = (float*)base;  base += 32768;
  float* xball = (float*)base;  base += 2097152;
  int*   cnt   = (int*)base;    base += 1024;

  hipLaunchKernelGGL(conv_pack, dim3(4368), dim3(256), 0, stream,
                     x, o_xj, o_xi, rel_o_xj, rel_o_xi, p_xj, p_xi,
                     xhi, xthi, wjhi, wihi, Wthi, Wtlo, colWs, bpart, cnt);
  hipLaunchKernelGGL(mfma_gemm, dim3(2048), dim3(256), 0, stream,
                     xhi, xthi, wjhi, wihi, Ttj, Tti, pJ, pI);
  hipLaunchKernelGGL(stage3_fused, dim3(512), dim3(256), 0, stream,
                     Ttj, Tti, Wthi, Wtlo, colWs, rel_p_xj, rel_p_xi, pJ, pI, bpart,
                     gamma_p, beta_p, xball, cnt, out);
}

// Round 13
// 103.762 us; speedup vs baseline: 1.6018x; 1.6018x over previous
//
#include <hip/hip_runtime.h>
#include <math.h>

static constexpr float EPSF = 1e-5f;

typedef short bf16x8 __attribute__((ext_vector_type(8)));
typedef float f32x4 __attribute__((ext_vector_type(4)));
typedef ushort u16x8 __attribute__((ext_vector_type(8)));

__device__ inline ushort bf16rn(float f) {
  unsigned u = __float_as_uint(f);
  unsigned r = (u + 0x7FFFu + ((u >> 16) & 1u)) >> 16;
  return (ushort)r;
}
__device__ inline float bf2f(ushort u) { return __uint_as_float(((unsigned)u) << 16); }
__device__ inline void split2(float f, ushort& hi, ushort& lo) {
  ushort h = bf16rn(f);
  float hf = bf2f(h);
  hi = h;
  lo = bf16rn(f - hf);
}
// tanh via hw exp+rcp: exact at saturation, ~1e-7 abs err
__device__ inline float fast_tanh(float x) {
  float e = __expf(2.f * x);
  return 1.f - 2.f * __builtin_amdgcn_rcpf(e + 1.f);
}

__device__ inline void gload16(const ushort* g, ushort* l) {
  __builtin_amdgcn_global_load_lds((const __attribute__((address_space(1))) void*)g,
                                   (__attribute__((address_space(3))) void*)l, 16, 0, 0);
}

// Tiled layout (ushort index): addr(row,k) = (row>>7)*65536 + (k>>5)*4096
//   + ((k>>3)&3)*1024 + (row&127)*8 + (k&7)
__device__ inline size_t tiled_addr(int row, int k) {
  return (size_t)(row >> 7) * 65536 + (size_t)(k >> 5) * 4096 +
         (size_t)((k >> 3) & 3) * 1024 + (size_t)(row & 127) * 8 + (k & 7);
}

// ---------------- K1: fused convx (0..4095) + pack_w (4096..4351) + pack_pw (4352..4367) ----------------
__global__ __launch_bounds__(256) void conv_pack(
    const float* __restrict__ x,
    const float* __restrict__ o_xj, const float* __restrict__ o_xi,
    const float* __restrict__ rel_o_xj, const float* __restrict__ rel_o_xi,
    const float* __restrict__ p_xj, const float* __restrict__ p_xi,
    ushort* __restrict__ xhi, ushort* __restrict__ xthi,
    ushort* __restrict__ wjhi, ushort* __restrict__ wihi,
    ushort* __restrict__ Wthi, ushort* __restrict__ Wtlo,
    float* __restrict__ colWs,
    float* __restrict__ bpart) {
  const int bx = blockIdx.x;
  const int tid = threadIdx.x;
  if (bx >= 4352) {
    // ---- pack_pw: p_xj/p_xi -> Wt[path][d][q][512] bf16 hi/lo + colWs ----
    const int pd = bx - 4352;            // 0..15
    const int path = pd >> 3, d = pd & 7;
    const float* src = (path ? p_xi : p_xj) + (size_t)d * 16384;
    ushort* whi = Wthi + (size_t)pd * 16384;
    ushort* wlo = Wtlo + (size_t)pd * 16384;
    __shared__ float buf[64][33];
    float cw = 0.f;
    const int q = tid >> 3, je8 = (tid & 7) * 8;
    for (int j0 = 0; j0 < 512; j0 += 64) {
      for (int l = tid; l < 2048; l += 256) buf[l >> 5][l & 31] = src[(size_t)j0 * 32 + l];
      __syncthreads();
      u16x8 h8, l8;
      #pragma unroll
      for (int e = 0; e < 8; ++e) {
        float fv = buf[je8 + e][q];
        cw += fv;
        ushort h, l; split2(fv, h, l);
        h8[e] = h; l8[e] = l;
      }
      *reinterpret_cast<u16x8*>(&whi[(size_t)q * 512 + j0 + je8]) = h8;
      *reinterpret_cast<u16x8*>(&wlo[(size_t)q * 512 + j0 + je8]) = l8;
      __syncthreads();
    }
    cw += __shfl_xor(cw, 1); cw += __shfl_xor(cw, 2); cw += __shfl_xor(cw, 4);
    if ((tid & 7) == 0) colWs[(size_t)pd * 32 + q] = cw;
    return;
  }
  if (bx >= 4096) {
    // ---- pack_w (o-weights, tiled bf16) ----
    int u = (bx - 4096) * 256 + tid;   // 0..65535
    int path = u >> 15;
    int v = u & 32767;
    int c = v >> 6;
    int k0 = (v & 63) * 8;
    int d = c >> 6, s = (c >> 5) & 1, p = c & 31;
    const float* src = path ? (s ? rel_o_xi : o_xi) : (s ? rel_o_xj : o_xj);
    u16x8 h8;
    #pragma unroll
    for (int e = 0; e < 8; ++e) h8[e] = bf16rn(src[((size_t)d * 512 + k0 + e) * 32 + p]);
    size_t a = tiled_addr(c, k0);
    ushort* whi = path ? wihi : wjhi;
    *reinterpret_cast<u16x8*>(&whi[a]) = h8;
    return;
  }
  // ---- convx part ----
  __shared__ float tile[64][65];
  __shared__ float wsum[4], wsq[4];
  const int ti = bx & 7, tj = (bx >> 3) & 7, b = bx >> 6;
  const int i0 = ti * 64, j0 = tj * 64;
  const float* xb = x + (size_t)b * 262144;
  const size_t obase = (size_t)b * 262144;
  const int tr = tid >> 4;
  const int tc = (tid & 15) * 4;
  float s = 0.f, s2 = 0.f;
  #pragma unroll
  for (int r = 0; r < 4; ++r) {
    const int row = r * 16 + tr;
    float4 v = *reinterpret_cast<const float4*>(&xb[(size_t)(i0 + row) * 512 + j0 + tc]);
    tile[row][tc + 0] = v.x; tile[row][tc + 1] = v.y;
    tile[row][tc + 2] = v.z; tile[row][tc + 3] = v.w;
    s += v.x + v.y + v.z + v.w;
    s2 += v.x * v.x + v.y * v.y + v.z * v.z + v.w * v.w;
  }
  // wave-level stat reduce (no barrier tree)
  #pragma unroll
  for (int m = 1; m < 64; m <<= 1) { s += __shfl_xor(s, m); s2 += __shfl_xor(s2, m); }
  if ((tid & 63) == 0) { wsum[tid >> 6] = s; wsq[tid >> 6] = s2; }
  __syncthreads();
  if (tid == 0) {
    float* pb = bpart + ((size_t)b * 64 + tj * 8 + ti) * 2;
    pb[0] = wsum[0] + wsum[1] + wsum[2] + wsum[3];
    pb[1] = wsq[0] + wsq[1] + wsq[2] + wsq[3];
  }
  const int kg = tid >> 5;   // 0..7
  const int rp = tid & 31;
  #pragma unroll
  for (int rr = 0; rr < 2; ++rr) {
    const int li = rp + rr * 32;
    u16x8 h8;
    #pragma unroll
    for (int e = 0; e < 8; ++e) h8[e] = bf16rn(tile[li][kg * 8 + e]);
    *reinterpret_cast<u16x8*>(&xhi[obase + tiled_addr(i0 + li, j0 + kg * 8)]) = h8;
  }
  #pragma unroll
  for (int rr = 0; rr < 2; ++rr) {
    const int lj = rp + rr * 32;
    u16x8 h8;
    #pragma unroll
    for (int e = 0; e < 8; ++e) h8[e] = bf16rn(tile[kg * 8 + e][lj]);
    *reinterpret_cast<u16x8*>(&xthi[obase + tiled_addr(j0 + lj, i0 + kg * 8)]) = h8;
  }
}

// ---------------- K2: pure-bf16 MFMA GEMM (R8-proven structure, BK=32) ----------------
// T output written TRANSPOSED: Tt[b][d][p 32][i 512] (bf16).
__global__ __launch_bounds__(256) void mfma_gemm(
    const ushort* __restrict__ xhi, const ushort* __restrict__ xthi,
    const ushort* __restrict__ wjhi, const ushort* __restrict__ wihi,
    ushort* __restrict__ Ttj, ushort* __restrict__ Tti,
    float* __restrict__ pJ, float* __restrict__ pI) {
  const int id = blockIdx.x;
  const int wid = (id & 7) * 256 + (id >> 3);   // XCD-aware swizzle (2048 = 8*256)
  const int ct = wid & 3, tm = (wid >> 2) & 3, bz = wid >> 4;
  const int b = bz >> 1, path = bz & 1;
  const ushort* Ahi = (path ? xthi : xhi) + (size_t)b * 262144 + (size_t)tm * 65536;
  const ushort* Bhi = (path ? wihi : wjhi) + (size_t)ct * 65536;
  ushort* Tb = (path ? Tti : Ttj) + (size_t)b * 131072;
  float* partial = path ? pI : pJ;

  __shared__ alignas(16) ushort As_hi[4096], Bs_hi[4096];
  __shared__ float rsum[4], rsq[4], rcol[4][32];

  const int tid = threadIdx.x;
  const int lane = tid & 63, w = tid >> 6;
  const int wr = w >> 1, wc = w & 1;
  const int m0 = tm * 128;

  const int L8 = (w * 64 + lane) * 8;
  const int ldsb0 = (w * 64) * 8;
  const int ldsb1 = 2048 + (w * 64) * 8;

  f32x4 acc[4][4] = {};
  const int fr = lane & 15;
  const int kc = lane >> 4;

  for (int ks = 0; ks < 16; ++ks) {
    const ushort* Ah = Ahi + ks * 4096;
    const ushort* Bh = Bhi + ks * 4096;
    gload16(Ah + L8,        &As_hi[ldsb0]);
    gload16(Ah + 2048 + L8, &As_hi[ldsb1]);
    gload16(Bh + L8,        &Bs_hi[ldsb0]);
    gload16(Bh + 2048 + L8, &Bs_hi[ldsb1]);
    __syncthreads();
    bf16x8 ah[4], bh[4];
    #pragma unroll
    for (int mi = 0; mi < 4; ++mi) {
      const int ra = (kc * 128 + wr * 64 + mi * 16 + fr) * 8;
      ah[mi] = *reinterpret_cast<const bf16x8*>(&As_hi[ra]);
    }
    #pragma unroll
    for (int ni = 0; ni < 4; ++ni) {
      const int rb = (kc * 128 + wc * 64 + ni * 16 + fr) * 8;
      bh[ni] = *reinterpret_cast<const bf16x8*>(&Bs_hi[rb]);
    }
    #pragma unroll
    for (int mi = 0; mi < 4; ++mi)
      #pragma unroll
      for (int ni = 0; ni < 4; ++ni)
        acc[mi][ni] = __builtin_amdgcn_mfma_f32_16x16x32_bf16(ah[mi], bh[ni], acc[mi][ni], 0, 0, 0);
    __syncthreads();
  }

  float lsum = 0.f, lsq = 0.f, cs0 = 0.f, cs1 = 0.f;
  const int d = ct * 2 + wc;
  #pragma unroll
  for (int mi = 0; mi < 4; ++mi) {
    const int rbase = m0 + wr * 64 + mi * 16 + ((lane >> 4) << 2);
    #pragma unroll
    for (int ni = 0; ni < 4; ++ni) {
      if (ni < 2) {
        const int p = ni * 16 + fr;
        float t0 = fast_tanh(acc[mi][ni][0]);
        float t1 = fast_tanh(acc[mi][ni][1]);
        float t2 = fast_tanh(acc[mi][ni][2]);
        float t3 = fast_tanh(acc[mi][ni][3]);
        lsum += t0 + t1 + t2 + t3;
        lsq += t0 * t0 + t1 * t1 + t2 * t2 + t3 * t3;
        ushort4 pk;
        pk.x = bf16rn(t0); pk.y = bf16rn(t1); pk.z = bf16rn(t2); pk.w = bf16rn(t3);
        *reinterpret_cast<ushort4*>(&Tb[((size_t)d * 32 + p) * 512 + rbase]) = pk;
      } else {
        #pragma unroll
        for (int r = 0; r < 4; ++r) {
          float e = __expf(acc[mi][ni][r]);
          if (ni == 2) cs0 += e; else cs1 += e;
        }
      }
    }
  }
  #pragma unroll
  for (int m = 1; m < 64; m <<= 1) { lsum += __shfl_xor(lsum, m); lsq += __shfl_xor(lsq, m); }
  cs0 += __shfl_xor(cs0, 16); cs0 += __shfl_xor(cs0, 32);
  cs1 += __shfl_xor(cs1, 16); cs1 += __shfl_xor(cs1, 32);
  if (lane == 0) { rsum[w] = lsum; rsq[w] = lsq; }
  if (lane < 16) { rcol[w][lane] = cs0; rcol[w][16 + lane] = cs1; }
  __syncthreads();
  if (tid < 64) {
    const int wc2 = tid >> 5, p = tid & 31;
    float* pb = partial + (((size_t)b * 4 + tm) * 8 + ct * 2 + wc2) * 34;
    pb[2 + p] = rcol[wc2][p] + rcol[wc2 + 2][p];
    if (p == 0) {
      pb[0] = rsum[wc2] + rsum[wc2 + 2];
      pb[1] = rsq[wc2] + rsq[wc2 + 2];
    }
  }
}

// ---------------- K3: fused stage3 (folds the gemm partials) ----------------
// Block per (b,d). Waves: w = path*2 + mt.
__global__ __launch_bounds__(256) void stage3_fused(
    const ushort* __restrict__ Ttj, const ushort* __restrict__ Tti,
    const ushort* __restrict__ Wthi, const ushort* __restrict__ Wtlo,
    const float* __restrict__ colWs,
    const float* __restrict__ rel_pj, const float* __restrict__ rel_pi,
    const float* __restrict__ pJ, const float* __restrict__ pI,
    const float* __restrict__ bpart,
    const float* __restrict__ gamma_p, const float* __restrict__ beta_p,
    float* __restrict__ xball) {
  const int bd = blockIdx.x;
  const int b = bd >> 3, d = bd & 7;
  const int tid = threadIdx.x;
  const int lane = tid & 63, w = tid >> 6;
  const int path = w >> 1, mt = w & 1;
  const int fr = lane & 15, kg = lane >> 4;

  __shared__ float Vl[2][32][33];
  __shared__ float Rl[2][32][32];
  __shared__ float cred[2][32][33];
  __shared__ float colw_s[64];
  __shared__ float stS[2][34];     // folded raw sums: [path]{sum,sumsq,col[32]}
  __shared__ float ms[2][2];       // [path]{mean, rstd}
  __shared__ float orelT[2];
  __shared__ float pred[4][2];
  __shared__ float csum[2][32];
  __shared__ float stot[2];
  __shared__ float fsc[2][32];
  __shared__ float red[256], red2[256];
  __shared__ float sred[2], sbst[2];

  // stage R matrices, colW, folded stats, batch stats
  for (int l = tid; l < 2048; l += 256) {
    const int pp = l >> 10, idx = l & 1023;
    const float* Rsrc = pp ? rel_pi : rel_pj;
    Rl[pp][idx >> 5][idx & 31] = Rsrc[(size_t)d * 1024 + idx];
  }
  if (tid < 64) colw_s[tid] = colWs[(((size_t)(tid >> 5) * 8 + d)) * 32 + (tid & 31)];
  if (tid >= 64 && tid < 132) {
    const int u = tid - 64;
    const int pp = u >= 34, t = pp ? u - 34 : u;
    const float* P = pp ? pI : pJ;
    float v = 0.f;
    #pragma unroll
    for (int tm2 = 0; tm2 < 4; ++tm2) v += P[(((size_t)b * 4 + tm2) * 8 + d) * 34 + t];
    stS[pp][t] = v;
  }
  if (tid >= 192) {
    const int t = tid - 192;
    float s = bpart[(size_t)b * 128 + t * 2];
    float s2 = bpart[(size_t)b * 128 + t * 2 + 1];
    #pragma unroll
    for (int m = 1; m < 64; m <<= 1) { s += __shfl_xor(s, m); s2 += __shfl_xor(s2, m); }
    if (t == 0) {
      const float N = 262144.f;
      float mean = s / N;
      float var = (s2 - s * s / N) / (N - 1.f);
      sbst[0] = mean * 256.f;
      sbst[1] = sqrtf(fmaxf(var, 0.f)) * 256.f;
    }
  }
  __syncthreads();
  if (tid < 2) {
    const float* S = stS[tid];
    const float N = 16384.f;
    float mean = S[0] / N;
    float var = (S[1] - S[0] * S[0] / N) / (N - 1.f);
    ms[tid][0] = mean;
    ms[tid][1] = 1.f / (sqrtf(fmaxf(var, 0.f)) + EPSF);
    float tot = 0.f;
    for (int k = 0; k < 32; ++k) tot += S[2 + k];
    orelT[tid] = tot;
  }

  // ---- MFMA projection: 16 rows (this wave) x 32 cols, K=512 ----
  f32x4 acc0 = {}, acc1 = {};
  const ushort* Whi_p = Wthi + ((size_t)path * 8 + d) * 16384;
  const ushort* Wlo_p = Wtlo + ((size_t)path * 8 + d) * 16384;
  const ushort* Tp = (path ? Tti : Ttj) + ((size_t)b * 8 + d) * 16384;

  if (path == 0) {
    const ushort* Arow = Tp + (size_t)(mt * 16 + fr) * 512;
    const ushort* B0h = Whi_p + (size_t)fr * 512;
    const ushort* B0l = Wlo_p + (size_t)fr * 512;
    const ushort* B1h = Whi_p + (size_t)(16 + fr) * 512;
    const ushort* B1l = Wlo_p + (size_t)(16 + fr) * 512;
    for (int k0 = 0; k0 < 512; k0 += 32) {
      const int ko = k0 + kg * 8;
      bf16x8 a   = *reinterpret_cast<const bf16x8*>(Arow + ko);
      bf16x8 b0h = *reinterpret_cast<const bf16x8*>(B0h + ko);
      bf16x8 b0l = *reinterpret_cast<const bf16x8*>(B0l + ko);
      bf16x8 b1h = *reinterpret_cast<const bf16x8*>(B1h + ko);
      bf16x8 b1l = *reinterpret_cast<const bf16x8*>(B1l + ko);
      acc0 = __builtin_amdgcn_mfma_f32_16x16x32_bf16(a, b0h, acc0, 0, 0, 0);
      acc0 = __builtin_amdgcn_mfma_f32_16x16x32_bf16(a, b0l, acc0, 0, 0, 0);
      acc1 = __builtin_amdgcn_mfma_f32_16x16x32_bf16(a, b1h, acc1, 0, 0, 0);
      acc1 = __builtin_amdgcn_mfma_f32_16x16x32_bf16(a, b1l, acc1, 0, 0, 0);
    }
  } else {
    const ushort* Ahr = Whi_p + (size_t)(mt * 16 + fr) * 512;
    const ushort* Alr = Wlo_p + (size_t)(mt * 16 + fr) * 512;
    const ushort* B0 = Tp + (size_t)fr * 512;
    const ushort* B1 = Tp + (size_t)(16 + fr) * 512;
    for (int k0 = 0; k0 < 512; k0 += 32) {
      const int ko = k0 + kg * 8;
      bf16x8 ah = *reinterpret_cast<const bf16x8*>(Ahr + ko);
      bf16x8 al = *reinterpret_cast<const bf16x8*>(Alr + ko);
      bf16x8 b0 = *reinterpret_cast<const bf16x8*>(B0 + ko);
      bf16x8 b1 = *reinterpret_cast<const bf16x8*>(B1 + ko);
      acc0 = __builtin_amdgcn_mfma_f32_16x16x32_bf16(ah, b0, acc0, 0, 0, 0);
      acc0 = __builtin_amdgcn_mfma_f32_16x16x32_bf16(al, b0, acc0, 0, 0, 0);
      acc1 = __builtin_amdgcn_mfma_f32_16x16x32_bf16(ah, b1, acc1, 0, 0, 0);
      acc1 = __builtin_amdgcn_mfma_f32_16x16x32_bf16(al, b1, acc1, 0, 0, 0);
    }
  }
  __syncthreads();   // ms/orelT ready (also covers stS)

  // ---- corrected standardize + tanh ----
  const float mean = ms[path][0], rstd = ms[path][1];
  float tv0[4], tv1[4];
  float ls = 0.f, lq = 0.f;
  #pragma unroll
  for (int r = 0; r < 4; ++r) {
    const int rowm = mt * 16 + kg * 4 + r;
    {
      const float cw = (path == 0) ? colw_s[fr] : colw_s[32 + rowm];
      float t = fast_tanh((acc0[r] - mean * cw) * rstd);
      tv0[r] = t; ls += t; lq += t * t;
    }
    {
      const float cw = (path == 0) ? colw_s[16 + fr] : colw_s[32 + rowm];
      float t = fast_tanh((acc1[r] - mean * cw) * rstd);
      tv1[r] = t; ls += t; lq += t * t;
    }
  }
  #pragma unroll
  for (int m = 1; m < 64; m <<= 1) { ls += __shfl_xor(ls, m); lq += __shfl_xor(lq, m); }
  if (lane == 0) { pred[w][0] = ls; pred[w][1] = lq; }
  __syncthreads();
  {
    const float S = pred[path * 2][0] + pred[path * 2 + 1][0];
    const float SS = pred[path * 2][1] + pred[path * 2 + 1][1];
    const float m2 = S / 1024.f;
    const float var = (SS - S * S / 1024.f) / 1023.f;
    const float r2 = 1.f / (sqrtf(fmaxf(var, 0.f)) + EPSF);
    #pragma unroll
    for (int r = 0; r < 4; ++r) {
      const int rowm = mt * 16 + kg * 4 + r;
      Vl[path][rowm][fr] = (tv0[r] - m2) * r2;
      Vl[path][rowm][16 + fr] = (tv1[r] - m2) * r2;
    }
  }
  __syncthreads();

  // ---- rel matmul + exp (128 threads per path) ----
  {
    const int t2 = tid & 127;
    const int prow = t2 >> 2, c8 = (t2 & 3) * 8;
    float racc[8] = {};
    #pragma unroll
    for (int c = 0; c < 32; ++c) {
      const float v = Vl[path][prow][c];
      #pragma unroll
      for (int e = 0; e < 8; ++e) racc[e] = fmaf(v, Rl[path][c][c8 + e], racc[e]);
    }
    #pragma unroll
    for (int e = 0; e < 8; ++e) cred[path][prow][c8 + e] = __expf(racc[e]);
  }
  __syncthreads();
  if (tid < 64) {
    const int pp = tid >> 5, q = tid & 31;
    float s = 0.f;
    #pragma unroll 8
    for (int p = 0; p < 32; ++p) s += cred[pp][p][q];
    csum[pp][q] = s;
  }
  __syncthreads();
  if (tid < 2) {
    float tot = 0.f;
    for (int k = 0; k < 32; ++k) tot += csum[tid][k];
    stot[tid] = tot;
  }
  __syncthreads();
  if (tid < 64) {
    const int pp = tid >> 5, q = tid & 31;
    fsc[pp][q] = sqrtf((stS[pp][2 + q] / orelT[pp]) * stot[pp] / csum[pp][q]);
  }
  __syncthreads();

  // ---- combine ----
  const int row = tid >> 3, c4 = (tid & 7) * 4;
  float xv[4]; float ls2 = 0.f, lq2 = 0.f;
  #pragma unroll
  for (int e = 0; e < 4; ++e) {
    const int q = c4 + e;
    float v = fast_tanh(Vl[0][row][q] * fsc[0][row] * Vl[1][q][row] * fsc[1][q]);
    xv[e] = v; ls2 += v; lq2 += v * v;
  }
  red[tid] = ls2; red2[tid] = lq2;
  __syncthreads();
  for (int off = 128; off > 0; off >>= 1) {
    if (tid < off) { red[tid] += red[tid + off]; red2[tid] += red2[tid + off]; }
    __syncthreads();
  }
  if (tid == 0) {
    float s = red[0], ss = red2[0];
    float m = s / 1024.f;
    float var = (ss - s * s / 1024.f) / 1023.f;
    sred[0] = m; sred[1] = 1.f / (sqrtf(fmaxf(var, 0.f)) + EPSF);
  }
  __syncthreads();
  const float m3 = sred[0], r3 = sred[1];
  const float xm = sbst[0], xs = sbst[1];
  const float g = gamma_p[d], be = beta_p[d];
  #pragma unroll
  for (int e = 0; e < 4; ++e) {
    float v = (xv[e] - m3) * r3 * xs + xm;
    xball[(size_t)bd * 1024 + row * 32 + c4 + e] = v * g + be;
  }
}

// ---------------- K4: sum over d / D (vectorized) ----------------
__global__ void final_kernel(const float* __restrict__ xball, float* __restrict__ out) {
  const int b = blockIdx.x;
  const int e4 = threadIdx.x * 4;   // 256 threads x 4 = 1024
  float4 s = make_float4(0.f, 0.f, 0.f, 0.f);
  #pragma unroll
  for (int d = 0; d < 8; ++d) {
    float4 v = *reinterpret_cast<const float4*>(&xball[((size_t)(b * 8 + d)) * 1024 + e4]);
    s.x += v.x; s.y += v.y; s.z += v.z; s.w += v.w;
  }
  s.x *= 0.125f; s.y *= 0.125f; s.z *= 0.125f; s.w *= 0.125f;
  *reinterpret_cast<float4*>(&out[(size_t)b * 1024 + e4]) = s;
}

extern "C" void kernel_launch(void* const* d_in, const int* in_sizes, int n_in,
                              void* d_out, int out_size, void* d_ws, size_t ws_size,
                              hipStream_t stream) {
  const float* x        = (const float*)d_in[0];
  const float* o_xj     = (const float*)d_in[1];
  const float* o_xi     = (const float*)d_in[2];
  const float* p_xj     = (const float*)d_in[3];
  const float* p_xi     = (const float*)d_in[4];
  const float* rel_o_xj = (const float*)d_in[5];
  const float* rel_o_xi = (const float*)d_in[6];
  const float* rel_p_xj = (const float*)d_in[7];
  const float* rel_p_xi = (const float*)d_in[8];
  const float* gamma_p  = (const float*)d_in[9];
  const float* beta_p   = (const float*)d_in[10];
  float* out = (float*)d_out;

  char* base = (char*)d_ws;
  ushort* xhi  = (ushort*)base; base += (size_t)33554432;
  ushort* xthi = (ushort*)base; base += (size_t)33554432;
  ushort* wjhi = (ushort*)base; base += 524288;
  ushort* wihi = (ushort*)base; base += 524288;
  ushort* Ttj  = (ushort*)base; base += (size_t)16777216;
  ushort* Tti  = (ushort*)base; base += (size_t)16777216;
  ushort* Wthi = (ushort*)base; base += 524288;
  ushort* Wtlo = (ushort*)base; base += 524288;
  float* colWs = (float*)base;  base += 2048;
  float* pJ    = (float*)base;  base += 278528;
  float* pI    = (float*)base;  base += 278528;
  float* bpart = (float*)base;  base += 32768;
  float* xball = (float*)base;  base += 2097152;

  hipLaunchKernelGGL(conv_pack, dim3(4368), dim3(256), 0, stream,
                     x, o_xj, o_xi, rel_o_xj, rel_o_xi, p_xj, p_xi,
                     xhi, xthi, wjhi, wihi, Wthi, Wtlo, colWs, bpart);
  hipLaunchKernelGGL(mfma_gemm, dim3(2048), dim3(256), 0, stream,
                     xhi, xthi, wjhi, wihi, Ttj, Tti, pJ, pI);
  hipLaunchKernelGGL(stage3_fused, dim3(512), dim3(256), 0, stream,
                     Ttj, Tti, Wthi, Wtlo, colWs, rel_p_xj, rel_p_xi, pJ, pI, bpart,
                     gamma_p, beta_p, xball);
  hipLaunchKernelGGL(final_kernel, dim3(64), dim3(256), 0, stream, xball, out);
}